// Round 14
// baseline (162.568 us; speedup 1.0000x reference)
//
#include <hip/hip_runtime.h>
#include <hip/hip_bf16.h>

// B=4, L=S=2048, D_MODEL=512, H=8, E=64.
// Pipeline (bf16 MFMA, fp32 accum):
//   1) prep_all: inputs f32->bf16 + weights f32->bf16^T in ONE launch
//   2) qkv_gemm: bf16 A, 64x128 tile, dbuf LDS, XCD-bijective 1D grid.
//      V written s-permuted (4-blocks 0,2,1,3 per 16-group) for zero-shuffle PV.
//   3) flash_attn: split-KV 512-thread blocks, ASYNC dbuf staging — counted
//      vmcnt(4) (never drain-to-0 mid-loop), split K/V stages issued right after
//      their buffer is consumed; lgkmcnt(0)+barrier arrival-syncs only.
//      Fixed-max exp2 softmax, zero-shuffle PV (b128 V reads), kZero C-in.
//   4) o_gemm: same dbuf core -> d_out fp32

typedef __attribute__((ext_vector_type(8))) short bf8_t;
typedef __attribute__((ext_vector_type(4))) float f4_t;
typedef __attribute__((ext_vector_type(16))) float f16_t;
typedef __attribute__((ext_vector_type(4))) unsigned int u32x4;

#define D_MODEL 512
#define HEADS 8
#define EDIM 64
#define LSEQ 2048
#define NBATCH 4
#define MTOT (NBATCH * LSEQ) /* 8192 */
#define N4 (MTOT * D_MODEL / 4) /* 1048576 = 2^20 */

static __device__ __forceinline__ unsigned short f2bf(float f) {
  union { float f; unsigned int u; } x;
  x.f = f;
  unsigned int u = x.u;
  u += 0x7FFFu + ((u >> 16) & 1u);  // RNE
  return (unsigned short)(u >> 16);
}

static __device__ __forceinline__ unsigned int pack2bf(float a, float b) {
  union { __hip_bfloat162 h; unsigned int u; } c;
  c.h.x = __float2bfloat16(a);
  c.h.y = __float2bfloat16(b);
  return c.u;
}

#define GLOAD_LDS(gptr, lptr)                                                        \
  __builtin_amdgcn_global_load_lds((const __attribute__((address_space(1))) void*)(gptr), \
                                   (__attribute__((address_space(3))) void*)(lptr), 16, 0, 0)

// ---- merged prep: blocks [0,12288) convert inputs; [12288,12544) transpose weights ----
__global__ void prep_all(const float* __restrict__ q, const float* __restrict__ k,
                         const float* __restrict__ v,
                         const float* __restrict__ Wq, const float* __restrict__ Wk,
                         const float* __restrict__ Wv, const float* __restrict__ Wo,
                         unsigned short* __restrict__ Xq, unsigned short* __restrict__ Xk,
                         unsigned short* __restrict__ Xv,
                         unsigned short* __restrict__ Wqt, unsigned short* __restrict__ Wkt,
                         unsigned short* __restrict__ Wvt, unsigned short* __restrict__ Wot) {
  __shared__ float tile[64][65];
  const int blk = blockIdx.x;
  if (blk < 12288) {
    int i = blk * 256 + threadIdx.x;     // 0 .. 3*N4
    int which = i >> 20;
    int idx = i & (N4 - 1);
    const float* in = (which == 0) ? q : (which == 1) ? k : v;
    unsigned short* out = (which == 0) ? Xq : (which == 1) ? Xk : Xv;
    float4 x = ((const float4*)in)[idx];
    ushort4 o;
    o.x = f2bf(x.x); o.y = f2bf(x.y); o.z = f2bf(x.z); o.w = f2bf(x.w);
    ((ushort4*)out)[idx] = o;
  } else {
    const int b = blk - 12288;           // 0..255
    const int which = b >> 6;
    const int b2 = b & 63;
    const int k0 = (b2 >> 3) * 64, n0 = (b2 & 7) * 64;
    const float* W = (which == 0) ? Wq : (which == 1) ? Wk : (which == 2) ? Wv : Wo;
    unsigned short* Wt = (which == 0) ? Wqt : (which == 1) ? Wkt : (which == 2) ? Wvt : Wot;
    const int tx = threadIdx.x & 63;
    const int ty = threadIdx.x >> 6;
#pragma unroll
    for (int i = 0; i < 64; i += 4)
      tile[i + ty][tx] = W[(size_t)(k0 + i + ty) * D_MODEL + n0 + tx];
    __syncthreads();
#pragma unroll
    for (int i = 0; i < 64; i += 4)
      Wt[(size_t)(n0 + i + ty) * D_MODEL + k0 + tx] = f2bf(tile[tx][i + ty]);
  }
}

// ---- staging helpers (bf16) ----
__device__ __forceinline__ void stage_a(const unsigned short* __restrict__ A,
                                        unsigned short* lA, int m0, int k0) {
  const int t = threadIdx.x;
  int rowA = t >> 2, cbA = (t & 3) * 16;
  GLOAD_LDS((const char*)(A + (size_t)(m0 + rowA) * D_MODEL + k0) + cbA, (char*)lA + t * 16);
}
__device__ __forceinline__ void stage_b(const unsigned short* __restrict__ Bt,
                                        unsigned short* lB, int n0, int k0) {
  const int t = threadIdx.x;
#pragma unroll
  for (int ii = 0; ii < 2; ++ii) {
    int c = t + ii * 256;
    int rowB = c >> 2, cbB = (c & 3) * 16;
    GLOAD_LDS((const char*)(Bt + (size_t)(n0 + rowB) * D_MODEL + k0) + cbB, (char*)lB + c * 16);
  }
}

// ---- GEMM mainloop: 64x128 tile, BK=32, double-buffered, 1 barrier/step ----
__device__ __forceinline__ void gemm_core(const unsigned short* __restrict__ A,
                                          const unsigned short* __restrict__ Bt,
                                          unsigned short* __restrict__ lAv,  // [2][64*32]
                                          unsigned short* __restrict__ lBv,  // [2][128*32]
                                          f4_t (&acc)[2][4], int m0, int n0) {
  const int t = threadIdx.x;
  const int lane = t & 63;
  const int w = t >> 6;
  const int wr = w >> 1, wc = w & 1;
  const int r = lane & 15, g = lane >> 4;
  const int ASZ = 64 * 32, BSZ = 128 * 32;

  stage_a(A, lAv, m0, 0);
  stage_b(Bt, lBv, n0, 0);
  __syncthreads();

  int cur = 0;
  const int NK = D_MODEL / 32;
  for (int ks = 0; ks < NK; ++ks) {
    if (ks + 1 < NK) {
      const int kn = (ks + 1) * 32;
      stage_a(A, lAv + (cur ^ 1) * ASZ, m0, kn);
      stage_b(Bt, lBv + (cur ^ 1) * BSZ, n0, kn);
    }

    bf8_t af[2], bfv[4];
    const unsigned short* lA = lAv + cur * ASZ;
#pragma unroll
    for (int mi = 0; mi < 2; ++mi)
      af[mi] = *(const bf8_t*)(lA + (wr * 32 + mi * 16 + r) * 32 + g * 8);
    const unsigned short* lB = lBv + cur * BSZ;
#pragma unroll
    for (int ni = 0; ni < 4; ++ni)
      bfv[ni] = *(const bf8_t*)(lB + (wc * 64 + ni * 16 + r) * 32 + g * 8);
#pragma unroll
    for (int mi = 0; mi < 2; ++mi)
#pragma unroll
      for (int ni = 0; ni < 4; ++ni)
        acc[mi][ni] = __builtin_amdgcn_mfma_f32_16x16x32_bf16(af[mi], bfv[ni], acc[mi][ni], 0, 0, 0);
    __syncthreads();
    cur ^= 1;
  }
}

// QKV: 1D grid 1536, XCD-bijective decode. 24KB LDS.
#define QSCALE 0.18033688011112042f /* 0.125 * log2(e) : exp2-domain scores */
__global__ __launch_bounds__(256, 6) void qkv_gemm(
    const unsigned short* __restrict__ Xq, const unsigned short* __restrict__ Xk,
    const unsigned short* __restrict__ Xv,
    const unsigned short* __restrict__ Wqt, const unsigned short* __restrict__ Wkt,
    const unsigned short* __restrict__ Wvt,
    const float* __restrict__ bq, const float* __restrict__ bk, const float* __restrict__ bv,
    unsigned short* __restrict__ Qh, unsigned short* __restrict__ Kh,
    unsigned short* __restrict__ Vt) {
  __shared__ alignas(16) unsigned short lA[2][64 * 32];
  __shared__ alignas(16) unsigned short lB[2][128 * 32];
  const int p = blockIdx.x;                 // 0..1535
  const int res = p & 7, q = p >> 3;
  const int xx = q & 3;
  const int grp = res + ((q >> 2) << 3);    // 0..383, bijective
  const int z = grp >> 7;                   // 0..2
  const int y = grp & 127;                  // 0..127
  const int n0 = xx * 128, m0 = y * 64;

  const unsigned short* A  = (z == 0) ? Xq : (z == 1) ? Xk : Xv;
  const unsigned short* Bt = (z == 0) ? Wqt : (z == 1) ? Wkt : Wvt;
  const float* bias        = (z == 0) ? bq : (z == 1) ? bk : bv;

  f4_t acc[2][4] = {};
  gemm_core(A, Bt, &lA[0][0], &lB[0][0], acc, m0, n0);

  const int lane = threadIdx.x & 63;
  const int w = threadIdx.x >> 6;
  const int wr = w >> 1, wc = w & 1;
  const int r = lane & 15, g = lane >> 4;
#pragma unroll
  for (int mi = 0; mi < 2; ++mi)
#pragma unroll
    for (int ni = 0; ni < 4; ++ni) {
      const int coln = n0 + wc * 64 + ni * 16 + r;
      const float bv_ = bias[coln];
      const int h = coln >> 6, e = coln & 63;
#pragma unroll
      for (int j = 0; j < 4; ++j) {
        const int rowm = m0 + wr * 32 + mi * 16 + g * 4 + j;
        const int b = rowm >> 11, li = rowm & 2047;
        float v = acc[mi][ni][j] + bv_;
        if (z == 0) {
          v *= QSCALE;
          Qh[(((size_t)(b * HEADS + h) * LSEQ + li) << 6) + e] = f2bf(v);
        } else if (z == 1) {
          Kh[(((size_t)(b * HEADS + h) * LSEQ + li) << 6) + e] = f2bf(v);
        } else {
          // V: permute s within each 16-group: 4-block b -> swap(b) (0,2,1,3)
          const int bb = (li >> 2) & 3;
          const int bs = ((bb & 1) << 1) | (bb >> 1);
          const int lp = (li & ~15) | (bs << 2) | (li & 3);
          Vt[(((size_t)(b * HEADS + h) * EDIM + e) << 11) + lp] = f2bf(v);
        }
      }
    }
}

// O-proj: 1D grid 512, same XCD-bijective decode. fp32 out.
__global__ __launch_bounds__(256, 6) void o_gemm(const unsigned short* __restrict__ A,
                                                 const unsigned short* __restrict__ Bt,
                                                 const float* __restrict__ bias,
                                                 float* __restrict__ Cout) {
  __shared__ alignas(16) unsigned short lA[2][64 * 32];
  __shared__ alignas(16) unsigned short lB[2][128 * 32];
  const int p = blockIdx.x;                 // 0..511
  const int res = p & 7, q = p >> 3;
  const int xx = q & 3;
  const int grp = res + ((q >> 2) << 3);    // 0..127
  const int n0 = xx * 128, m0 = grp * 64;

  f4_t acc[2][4] = {};
  gemm_core(A, Bt, &lA[0][0], &lB[0][0], acc, m0, n0);

  const int lane = threadIdx.x & 63;
  const int w = threadIdx.x >> 6;
  const int wr = w >> 1, wc = w & 1;
  const int r = lane & 15, g = lane >> 4;
#pragma unroll
  for (int mi = 0; mi < 2; ++mi)
#pragma unroll
    for (int ni = 0; ni < 4; ++ni) {
      const int coln = n0 + wc * 64 + ni * 16 + r;
      const float bv_ = bias[coln];
#pragma unroll
      for (int j = 0; j < 4; ++j) {
        const int rowm = m0 + wr * 32 + mi * 16 + g * 4 + j;
        Cout[(size_t)rowm * D_MODEL + coln] = acc[mi][ni][j] + bv_;
      }
    }
}

// ---------------- flash attention (split-KV, ASYNC LDS pipeline, fixed-max) ----------
// 1D grid 512, block 512 = 8 waves = 2 wave-groups of 4. XCD decode pins 4 heads/XCD.
// Per iter: {read K frags; lgkmcnt(0)+barrier; issue stage_K(t+2) into same buf;
// QK+softmax; PV (V b128 reads); lgkmcnt(0)+barrier; issue stage_V(t+2);
// vmcnt(4)+barrier}. vmcnt(4) => stage(t+1) retired (FIFO), stage(t+2) in flight —
// no drain-to-0 mid-loop. Barrier counts uniform across both wave-groups.
#define XSTR 68

__device__ __forceinline__ void stage_K(const unsigned short* __restrict__ Kbase,
                                        unsigned short* ldsK, int s0, int tg) {
#pragma unroll
  for (int ii = 0; ii < 2; ++ii) {
    int c = tg + ii * 256;
    int row = c >> 3, col = c & 7;
    int colp = col ^ (row & 7);      // involution: pre-swizzled source
    GLOAD_LDS((const char*)(Kbase + (size_t)(s0 + row) * EDIM + colp * 8),
              (char*)ldsK + c * 16);
  }
}
__device__ __forceinline__ void stage_V(const unsigned short* __restrict__ Vbase,
                                        unsigned short* ldsV, int s0, int tg) {
#pragma unroll
  for (int ii = 0; ii < 2; ++ii) {
    int c = tg + ii * 256;
    int row = c >> 3, col = c & 7;
    int colp = col ^ (row & 7);
    GLOAD_LDS((const char*)(Vbase + (size_t)row * LSEQ + s0 + colp * 8),
              (char*)ldsV + c * 16);
  }
}

__global__ __launch_bounds__(512, 4) void flash_attn(const unsigned short* __restrict__ Qh,
                                                     const unsigned short* __restrict__ Kh,
                                                     const unsigned short* __restrict__ Vt,
                                                     unsigned short* __restrict__ Ao) {
  __shared__ alignas(16) unsigned short stg[2][2][2][64 * 64];  // [wg][buf][K/V] = 64KB

  const int t = threadIdx.x;
  const int lane = t & 63;
  const int w = t >> 6;          // 0..7
  const int wg = w >> 2;         // KV half
  const int wq = w & 3;          // q sub-block
  const int tg = t & 255;        // thread index within group
  const int qn = lane & 31;
  const int hi = lane >> 5;
  const int p = blockIdx.x;      // 0..511
  const int xcd = p & 7, jj = p >> 3;
  const int bh = xcd * 4 + (jj >> 4);   // 4 heads per XCD
  const int qblk = jj & 15;
  const int q0 = qblk * 128 + wq * 32;
  const int sbase = wg * (LSEQ / 2);

  bf8_t qf[4];
#pragma unroll
  for (int kst = 0; kst < 4; ++kst)
    qf[kst] = *(const bf8_t*)(Qh + ((size_t)bh * LSEQ + q0 + qn) * EDIM + kst * 16 + hi * 8);

  float l_lane = 0.f;
  f16_t oacc[2];
#pragma unroll
  for (int eh = 0; eh < 2; ++eh)
#pragma unroll
    for (int r = 0; r < 16; ++r) oacc[eh][r] = 0.f;

  // persistent zero C-in for the first QK MFMA of each tile
  f16_t kZero;
#pragma unroll
  for (int r = 0; r < 16; ++r) kZero[r] = 0.f;

  const unsigned short* Kbase = Kh + (size_t)bh * LSEQ * EDIM;
  const unsigned short* Vbase = Vt + (size_t)bh * EDIM * LSEQ;

  // prologue: tiles 0 and 1 in flight; wait for tile 0 (4 newest stay in flight)
  stage_K(Kbase, stg[wg][0][0], sbase, tg);
  stage_V(Vbase, stg[wg][0][1], sbase, tg);
  stage_K(Kbase, stg[wg][1][0], sbase + 64, tg);
  stage_V(Vbase, stg[wg][1][1], sbase + 64, tg);
  asm volatile("s_waitcnt vmcnt(4)" ::: "memory");
  __builtin_amdgcn_s_barrier();
  __builtin_amdgcn_sched_barrier(0);

  const int NT = LSEQ / 2 / 64;  // 16 tiles per group
#pragma unroll 2
  for (int kt = 0; kt < NT; ++kt) {
    const int cur = kt & 1;
    const unsigned short* lsK = stg[wg][cur][0];
    const unsigned short* lsV = stg[wg][cur][1];

    // ---- read K frags (tile kt guaranteed resident) ----
    bf8_t kf[2][4];
#pragma unroll
    for (int sh = 0; sh < 2; ++sh)
#pragma unroll
      for (int kst = 0; kst < 4; ++kst) {
        const int row = 32 * sh + qn;
        const int ch = (2 * kst + hi) ^ (row & 7);
        kf[sh][kst] = *(const bf8_t*)(&lsK[row * 64 + ch * 8]);
      }
    asm volatile("s_waitcnt lgkmcnt(0)" ::: "memory");
    __builtin_amdgcn_sched_barrier(0);
    __builtin_amdgcn_s_barrier();            // all waves done reading K(kt)
    __builtin_amdgcn_sched_barrier(0);
    if (kt + 2 < NT) stage_K(Kbase, stg[wg][cur][0], sbase + (kt + 2) * 64, tg);

    // ---- QK^T (kZero C-in) ----
    f16_t sacc[2];
#pragma unroll
    for (int sh = 0; sh < 2; ++sh) {
      sacc[sh] = __builtin_amdgcn_mfma_f32_32x32x16_bf16(kf[sh][0], qf[0], kZero, 0, 0, 0);
#pragma unroll
      for (int kst = 1; kst < 4; ++kst)
        sacc[sh] = __builtin_amdgcn_mfma_f32_32x32x16_bf16(kf[sh][kst], qf[kst], sacc[sh], 0, 0, 0);
    }

    // ---- softmax numerator: P = 2^S2 (fixed max), l per-lane ----
    unsigned int pk[16];
#pragma unroll
    for (int sh = 0; sh < 2; ++sh)
#pragma unroll
      for (int i = 0; i < 8; ++i) {
        const float a = __builtin_amdgcn_exp2f(sacc[sh][2 * i]);
        const float b = __builtin_amdgcn_exp2f(sacc[sh][2 * i + 1]);
        l_lane += a + b;
        pk[sh * 8 + i] = pack2bf(a, b);
      }

    // ---- PV B-frags: zero-shuffle — lane's own pk words ----
    bf8_t pvb[4];
#pragma unroll
    for (int t2 = 0; t2 < 4; ++t2) {
      union { u32x4 u; bf8_t b; } pb;
      pb.u[0] = pk[4 * t2 + 0];
      pb.u[1] = pk[4 * t2 + 1];
      pb.u[2] = pk[4 * t2 + 2];
      pb.u[3] = pk[4 * t2 + 3];
      pvb[t2] = pb.b;
    }

    // ---- PV: V A-frag = ONE b128 (s-permuted storage) ----
#pragma unroll
    for (int eh = 0; eh < 2; ++eh)
#pragma unroll
      for (int t2 = 0; t2 < 4; ++t2) {
        const int row = 32 * eh + qn;
        const int ch = (2 * t2 + hi) ^ (row & 7);
        const bf8_t vf = *(const bf8_t*)(&lsV[row * 64 + ch * 8]);
        oacc[eh] = __builtin_amdgcn_mfma_f32_32x32x16_bf16(vf, pvb[t2], oacc[eh], 0, 0, 0);
      }
    asm volatile("s_waitcnt lgkmcnt(0)" ::: "memory");
    __builtin_amdgcn_sched_barrier(0);
    __builtin_amdgcn_s_barrier();            // all waves done reading V(kt)
    __builtin_amdgcn_sched_barrier(0);
    if (kt + 2 < NT) stage_V(Vbase, stg[wg][cur][1], sbase + (kt + 2) * 64, tg);

    // ---- ensure tile kt+1 resident before next iteration's reads ----
    if (kt + 2 < NT) {
      asm volatile("s_waitcnt vmcnt(4)" ::: "memory");   // t+2 (4 loads) may remain
    } else if (kt + 1 < NT) {
      asm volatile("s_waitcnt vmcnt(0)" ::: "memory");   // tail: drain everything
    }
    __builtin_amdgcn_s_barrier();
    __builtin_amdgcn_sched_barrier(0);
  }

  __syncthreads();   // stg reused below

  // ---- combine the two KV halves through LDS (additive: fixed max) ----
  const float l_own = l_lane + __shfl_xor(l_lane, 32);
  float* xO = (float*)&stg[0][0][0][0];        // [128 q][XSTR] floats
  float* xL = xO + 128 * XSTR;                 // [128] floats

  if (wg == 1) {
#pragma unroll
    for (int eh = 0; eh < 2; ++eh)
#pragma unroll
      for (int k = 0; k < 4; ++k) {
        float4 v4;
        v4.x = oacc[eh][4 * k + 0]; v4.y = oacc[eh][4 * k + 1];
        v4.z = oacc[eh][4 * k + 2]; v4.w = oacc[eh][4 * k + 3];
        *(float4*)(xO + (wq * 32 + qn) * XSTR + 32 * eh + 8 * k + 4 * hi) = v4;
      }
    if (hi == 0) xL[wq * 32 + qn] = l_own;
  }
  __syncthreads();

  if (wg == 0) {
    const float inv = 1.f / (l_own + xL[wq * 32 + qn]);
    const int b = bh >> 3, h = bh & 7;
#pragma unroll
    for (int eh = 0; eh < 2; ++eh)
#pragma unroll
      for (int k = 0; k < 4; ++k) {
        const float4 v4 = *(const float4*)(xO + (wq * 32 + qn) * XSTR + 32 * eh + 8 * k + 4 * hi);
        ushort4 ov;
        ov.x = f2bf((oacc[eh][4 * k + 0] + v4.x) * inv);
        ov.y = f2bf((oacc[eh][4 * k + 1] + v4.y) * inv);
        ov.z = f2bf((oacc[eh][4 * k + 2] + v4.z) * inv);
        ov.w = f2bf((oacc[eh][4 * k + 3] + v4.w) * inv);
        const int e = 32 * eh + 8 * k + 4 * hi;
        *(ushort4*)(Ao + ((size_t)(b * LSEQ + q0 + qn)) * D_MODEL + h * EDIM + e) = ov;
      }
  }
}

extern "C" void kernel_launch(void* const* d_in, const int* in_sizes, int n_in,
                              void* d_out, int out_size, void* d_ws, size_t ws_size,
                              hipStream_t stream) {
  const float* queries = (const float*)d_in[0];
  const float* keys    = (const float*)d_in[1];
  const float* values  = (const float*)d_in[2];
  const float* Wq = (const float*)d_in[3];
  const float* bq = (const float*)d_in[4];
  const float* Wk = (const float*)d_in[5];
  const float* bk = (const float*)d_in[6];
  const float* Wv = (const float*)d_in[7];
  const float* bv = (const float*)d_in[8];
  const float* Wo = (const float*)d_in[9];
  const float* bo = (const float*)d_in[10];

  char* ws = (char*)d_ws;
  const size_t XSZ = (size_t)MTOT * D_MODEL * 2;  // 8 MB
  unsigned short* Xq  = (unsigned short*)(ws + 0 * XSZ);
  unsigned short* Xk  = (unsigned short*)(ws + 1 * XSZ);
  unsigned short* Xv  = (unsigned short*)(ws + 2 * XSZ);
  unsigned short* Qh  = (unsigned short*)(ws + 3 * XSZ);
  unsigned short* Kh  = (unsigned short*)(ws + 4 * XSZ);
  unsigned short* Vt  = (unsigned short*)(ws + 5 * XSZ);
  unsigned short* Ao  = (unsigned short*)(ws + 6 * XSZ);
  unsigned short* Wqt = (unsigned short*)(ws + 7 * XSZ);
  unsigned short* Wkt = Wqt + 512 * 512;
  unsigned short* Wvt = Wkt + 512 * 512;
  unsigned short* Wot = Wvt + 512 * 512;

  prep_all<<<12544, 256, 0, stream>>>(queries, keys, values, Wq, Wk, Wv, Wo,
                                      Xq, Xk, Xv, Wqt, Wkt, Wvt, Wot);

  qkv_gemm<<<1536, 256, 0, stream>>>(
      Xq, Xk, Xv, Wqt, Wkt, Wvt, bq, bk, bv, Qh, Kh, Vt);

  flash_attn<<<512, 512, 0, stream>>>(Qh, Kh, Vt, Ao);

  o_gemm<<<512, 256, 0, stream>>>(Ao, Wot, bo, (float*)d_out);
}

// Round 15
// 101.099 us; speedup vs baseline: 1.6080x; 1.6080x over previous
//
#include <hip/hip_runtime.h>
#include <hip/hip_bf16.h>

// B=4, L=S=2048, D_MODEL=512, H=8, E=64.
// Pipeline (bf16 MFMA, fp32 accum):
//   1) prep_all: inputs f32->bf16 + weights f32->bf16^T in ONE launch
//   2) qkv_gemm: bf16 A, 64x128 tile, dbuf LDS, XCD-bijective 1D grid.
//      V written s-permuted (4-blocks 0,2,1,3 per 16-group) for zero-shuffle PV.
//   3) flash_attn: 1024-thread blocks (8 q-waves x 2 KV-groups), TRIPLE-buffered
//      LDS staging with counted vmcnt(2) — stage(t+2) never collides with reads,
//      so NO mid-body fences (r14's spill cause); one barrier per iter.
//      Fixed-max exp2 softmax, zero-shuffle PV (b128 V reads), kZero C-in.
//   4) o_gemm: same dbuf core -> d_out fp32

typedef __attribute__((ext_vector_type(8))) short bf8_t;
typedef __attribute__((ext_vector_type(4))) float f4_t;
typedef __attribute__((ext_vector_type(16))) float f16_t;
typedef __attribute__((ext_vector_type(4))) unsigned int u32x4;

#define D_MODEL 512
#define HEADS 8
#define EDIM 64
#define LSEQ 2048
#define NBATCH 4
#define MTOT (NBATCH * LSEQ) /* 8192 */
#define N4 (MTOT * D_MODEL / 4) /* 1048576 = 2^20 */

static __device__ __forceinline__ unsigned short f2bf(float f) {
  union { float f; unsigned int u; } x;
  x.f = f;
  unsigned int u = x.u;
  u += 0x7FFFu + ((u >> 16) & 1u);  // RNE
  return (unsigned short)(u >> 16);
}

static __device__ __forceinline__ unsigned int pack2bf(float a, float b) {
  union { __hip_bfloat162 h; unsigned int u; } c;
  c.h.x = __float2bfloat16(a);
  c.h.y = __float2bfloat16(b);
  return c.u;
}

#define GLOAD_LDS(gptr, lptr)                                                        \
  __builtin_amdgcn_global_load_lds((const __attribute__((address_space(1))) void*)(gptr), \
                                   (__attribute__((address_space(3))) void*)(lptr), 16, 0, 0)

// ---- merged prep: blocks [0,12288) convert inputs; [12288,12544) transpose weights ----
__global__ void prep_all(const float* __restrict__ q, const float* __restrict__ k,
                         const float* __restrict__ v,
                         const float* __restrict__ Wq, const float* __restrict__ Wk,
                         const float* __restrict__ Wv, const float* __restrict__ Wo,
                         unsigned short* __restrict__ Xq, unsigned short* __restrict__ Xk,
                         unsigned short* __restrict__ Xv,
                         unsigned short* __restrict__ Wqt, unsigned short* __restrict__ Wkt,
                         unsigned short* __restrict__ Wvt, unsigned short* __restrict__ Wot) {
  __shared__ float tile[64][65];
  const int blk = blockIdx.x;
  if (blk < 12288) {
    int i = blk * 256 + threadIdx.x;     // 0 .. 3*N4
    int which = i >> 20;
    int idx = i & (N4 - 1);
    const float* in = (which == 0) ? q : (which == 1) ? k : v;
    unsigned short* out = (which == 0) ? Xq : (which == 1) ? Xk : Xv;
    float4 x = ((const float4*)in)[idx];
    ushort4 o;
    o.x = f2bf(x.x); o.y = f2bf(x.y); o.z = f2bf(x.z); o.w = f2bf(x.w);
    ((ushort4*)out)[idx] = o;
  } else {
    const int b = blk - 12288;           // 0..255
    const int which = b >> 6;
    const int b2 = b & 63;
    const int k0 = (b2 >> 3) * 64, n0 = (b2 & 7) * 64;
    const float* W = (which == 0) ? Wq : (which == 1) ? Wk : (which == 2) ? Wv : Wo;
    unsigned short* Wt = (which == 0) ? Wqt : (which == 1) ? Wkt : (which == 2) ? Wvt : Wot;
    const int tx = threadIdx.x & 63;
    const int ty = threadIdx.x >> 6;
#pragma unroll
    for (int i = 0; i < 64; i += 4)
      tile[i + ty][tx] = W[(size_t)(k0 + i + ty) * D_MODEL + n0 + tx];
    __syncthreads();
#pragma unroll
    for (int i = 0; i < 64; i += 4)
      Wt[(size_t)(n0 + i + ty) * D_MODEL + k0 + tx] = f2bf(tile[tx][i + ty]);
  }
}

// ---- staging helpers (bf16) ----
__device__ __forceinline__ void stage_a(const unsigned short* __restrict__ A,
                                        unsigned short* lA, int m0, int k0) {
  const int t = threadIdx.x;
  int rowA = t >> 2, cbA = (t & 3) * 16;
  GLOAD_LDS((const char*)(A + (size_t)(m0 + rowA) * D_MODEL + k0) + cbA, (char*)lA + t * 16);
}
__device__ __forceinline__ void stage_b(const unsigned short* __restrict__ Bt,
                                        unsigned short* lB, int n0, int k0) {
  const int t = threadIdx.x;
#pragma unroll
  for (int ii = 0; ii < 2; ++ii) {
    int c = t + ii * 256;
    int rowB = c >> 2, cbB = (c & 3) * 16;
    GLOAD_LDS((const char*)(Bt + (size_t)(n0 + rowB) * D_MODEL + k0) + cbB, (char*)lB + c * 16);
  }
}

// ---- GEMM mainloop: 64x128 tile, BK=32, double-buffered, 1 barrier/step ----
__device__ __forceinline__ void gemm_core(const unsigned short* __restrict__ A,
                                          const unsigned short* __restrict__ Bt,
                                          unsigned short* __restrict__ lAv,  // [2][64*32]
                                          unsigned short* __restrict__ lBv,  // [2][128*32]
                                          f4_t (&acc)[2][4], int m0, int n0) {
  const int t = threadIdx.x;
  const int lane = t & 63;
  const int w = t >> 6;
  const int wr = w >> 1, wc = w & 1;
  const int r = lane & 15, g = lane >> 4;
  const int ASZ = 64 * 32, BSZ = 128 * 32;

  stage_a(A, lAv, m0, 0);
  stage_b(Bt, lBv, n0, 0);
  __syncthreads();

  int cur = 0;
  const int NK = D_MODEL / 32;
  for (int ks = 0; ks < NK; ++ks) {
    if (ks + 1 < NK) {
      const int kn = (ks + 1) * 32;
      stage_a(A, lAv + (cur ^ 1) * ASZ, m0, kn);
      stage_b(Bt, lBv + (cur ^ 1) * BSZ, n0, kn);
    }

    bf8_t af[2], bfv[4];
    const unsigned short* lA = lAv + cur * ASZ;
#pragma unroll
    for (int mi = 0; mi < 2; ++mi)
      af[mi] = *(const bf8_t*)(lA + (wr * 32 + mi * 16 + r) * 32 + g * 8);
    const unsigned short* lB = lBv + cur * BSZ;
#pragma unroll
    for (int ni = 0; ni < 4; ++ni)
      bfv[ni] = *(const bf8_t*)(lB + (wc * 64 + ni * 16 + r) * 32 + g * 8);
#pragma unroll
    for (int mi = 0; mi < 2; ++mi)
#pragma unroll
      for (int ni = 0; ni < 4; ++ni)
        acc[mi][ni] = __builtin_amdgcn_mfma_f32_16x16x32_bf16(af[mi], bfv[ni], acc[mi][ni], 0, 0, 0);
    __syncthreads();
    cur ^= 1;
  }
}

// QKV: 1D grid 1536, XCD-bijective decode. 24KB LDS.
#define QSCALE 0.18033688011112042f /* 0.125 * log2(e) : exp2-domain scores */
__global__ __launch_bounds__(256, 6) void qkv_gemm(
    const unsigned short* __restrict__ Xq, const unsigned short* __restrict__ Xk,
    const unsigned short* __restrict__ Xv,
    const unsigned short* __restrict__ Wqt, const unsigned short* __restrict__ Wkt,
    const unsigned short* __restrict__ Wvt,
    const float* __restrict__ bq, const float* __restrict__ bk, const float* __restrict__ bv,
    unsigned short* __restrict__ Qh, unsigned short* __restrict__ Kh,
    unsigned short* __restrict__ Vt) {
  __shared__ alignas(16) unsigned short lA[2][64 * 32];
  __shared__ alignas(16) unsigned short lB[2][128 * 32];
  const int p = blockIdx.x;                 // 0..1535
  const int res = p & 7, q = p >> 3;
  const int xx = q & 3;
  const int grp = res + ((q >> 2) << 3);    // 0..383, bijective
  const int z = grp >> 7;                   // 0..2
  const int y = grp & 127;                  // 0..127
  const int n0 = xx * 128, m0 = y * 64;

  const unsigned short* A  = (z == 0) ? Xq : (z == 1) ? Xk : Xv;
  const unsigned short* Bt = (z == 0) ? Wqt : (z == 1) ? Wkt : Wvt;
  const float* bias        = (z == 0) ? bq : (z == 1) ? bk : bv;

  f4_t acc[2][4] = {};
  gemm_core(A, Bt, &lA[0][0], &lB[0][0], acc, m0, n0);

  const int lane = threadIdx.x & 63;
  const int w = threadIdx.x >> 6;
  const int wr = w >> 1, wc = w & 1;
  const int r = lane & 15, g = lane >> 4;
#pragma unroll
  for (int mi = 0; mi < 2; ++mi)
#pragma unroll
    for (int ni = 0; ni < 4; ++ni) {
      const int coln = n0 + wc * 64 + ni * 16 + r;
      const float bv_ = bias[coln];
      const int h = coln >> 6, e = coln & 63;
#pragma unroll
      for (int j = 0; j < 4; ++j) {
        const int rowm = m0 + wr * 32 + mi * 16 + g * 4 + j;
        const int b = rowm >> 11, li = rowm & 2047;
        float v = acc[mi][ni][j] + bv_;
        if (z == 0) {
          v *= QSCALE;
          Qh[(((size_t)(b * HEADS + h) * LSEQ + li) << 6) + e] = f2bf(v);
        } else if (z == 1) {
          Kh[(((size_t)(b * HEADS + h) * LSEQ + li) << 6) + e] = f2bf(v);
        } else {
          // V: permute s within each 16-group: 4-block b -> swap(b) (0,2,1,3)
          const int bb = (li >> 2) & 3;
          const int bs = ((bb & 1) << 1) | (bb >> 1);
          const int lp = (li & ~15) | (bs << 2) | (li & 3);
          Vt[(((size_t)(b * HEADS + h) * EDIM + e) << 11) + lp] = f2bf(v);
        }
      }
    }
}

// O-proj: 1D grid 512, same XCD-bijective decode. fp32 out.
__global__ __launch_bounds__(256, 6) void o_gemm(const unsigned short* __restrict__ A,
                                                 const unsigned short* __restrict__ Bt,
                                                 const float* __restrict__ bias,
                                                 float* __restrict__ Cout) {
  __shared__ alignas(16) unsigned short lA[2][64 * 32];
  __shared__ alignas(16) unsigned short lB[2][128 * 32];
  const int p = blockIdx.x;                 // 0..511
  const int res = p & 7, q = p >> 3;
  const int xx = q & 3;
  const int grp = res + ((q >> 2) << 3);    // 0..127
  const int n0 = xx * 128, m0 = grp * 64;

  f4_t acc[2][4] = {};
  gemm_core(A, Bt, &lA[0][0], &lB[0][0], acc, m0, n0);

  const int lane = threadIdx.x & 63;
  const int w = threadIdx.x >> 6;
  const int wr = w >> 1, wc = w & 1;
  const int r = lane & 15, g = lane >> 4;
#pragma unroll
  for (int mi = 0; mi < 2; ++mi)
#pragma unroll
    for (int ni = 0; ni < 4; ++ni) {
      const int coln = n0 + wc * 64 + ni * 16 + r;
      const float bv_ = bias[coln];
#pragma unroll
      for (int j = 0; j < 4; ++j) {
        const int rowm = m0 + wr * 32 + mi * 16 + g * 4 + j;
        Cout[(size_t)rowm * D_MODEL + coln] = acc[mi][ni][j] + bv_;
      }
    }
}

// ---------------- flash attention (split-KV, TRIPLE-buffered async, fixed-max) -------
// 1D grid 256, block 1024 = 16 waves = 8 q-waves x 2 KV-groups. XCD pins 4 heads/XCD.
// Triple buffer: iter t reads buf t%3, stages t+2 into (t+2)%3 (no collision with
// t%3 or (t+1)%3 -> no mid-body fences). End of iter: vmcnt(2)+lgkmcnt(0)+barrier:
// retires stage(t+1) (FIFO), leaves stage(t+2) in flight. Buf t%3 is overwritten
// by stage(t+3) only after the iter-t barrier. Compute code identical to r13.
#define XSTR 68

__device__ __forceinline__ void stage_K1(const unsigned short* __restrict__ Kbase,
                                         unsigned short* ldsK, int s0, int tg) {
  int row = tg >> 3, col = tg & 7;
  int colp = col ^ (row & 7);      // involution: pre-swizzled source
  GLOAD_LDS((const char*)(Kbase + (size_t)(s0 + row) * EDIM + colp * 8),
            (char*)ldsK + tg * 16);
}
__device__ __forceinline__ void stage_V1(const unsigned short* __restrict__ Vbase,
                                         unsigned short* ldsV, int s0, int tg) {
  int row = tg >> 3, col = tg & 7;
  int colp = col ^ (row & 7);
  GLOAD_LDS((const char*)(Vbase + (size_t)row * LSEQ + s0 + colp * 8),
            (char*)ldsV + tg * 16);
}

__global__ __launch_bounds__(1024, 4) void flash_attn(const unsigned short* __restrict__ Qh,
                                                      const unsigned short* __restrict__ Kh,
                                                      const unsigned short* __restrict__ Vt,
                                                      unsigned short* __restrict__ Ao) {
  __shared__ alignas(16) unsigned short stg[2][3][2][64 * 64];  // 96 KB

  const int t = threadIdx.x;
  const int lane = t & 63;
  const int w = t >> 6;          // 0..15
  const int wg = w >> 3;         // KV half
  const int wq = w & 7;          // q sub-block
  const int tg = t & 511;        // thread index within group
  const int qn = lane & 31;
  const int hi = lane >> 5;
  const int p = blockIdx.x;      // 0..255
  const int xcd = p & 7, jj = p >> 3;
  const int bh = xcd * 4 + (jj >> 3);   // 4 heads per XCD
  const int qblk = jj & 7;
  const int q0 = qblk * 256 + wq * 32;
  const int sbase = wg * (LSEQ / 2);

  bf8_t qf[4];
#pragma unroll
  for (int kst = 0; kst < 4; ++kst)
    qf[kst] = *(const bf8_t*)(Qh + ((size_t)bh * LSEQ + q0 + qn) * EDIM + kst * 16 + hi * 8);

  float l_lane = 0.f;
  f16_t oacc[2];
#pragma unroll
  for (int eh = 0; eh < 2; ++eh)
#pragma unroll
    for (int r = 0; r < 16; ++r) oacc[eh][r] = 0.f;

  f16_t kZero;
#pragma unroll
  for (int r = 0; r < 16; ++r) kZero[r] = 0.f;

  const unsigned short* Kbase = Kh + (size_t)bh * LSEQ * EDIM;
  const unsigned short* Vbase = Vt + (size_t)bh * EDIM * LSEQ;

  // rotating buffer pointers: rd = t%3, nx = (t+1)%3, st = (t+2)%3
  unsigned short *rK = &stg[wg][0][0][0], *rV = &stg[wg][0][1][0];
  unsigned short *nK = &stg[wg][1][0][0], *nV = &stg[wg][1][1][0];
  unsigned short *sK = &stg[wg][2][0][0], *sV = &stg[wg][2][1][0];

  // prologue: stage tiles 0,1; wait for tile 0 (tile 1's 2 loads stay in flight)
  stage_K1(Kbase, rK, sbase, tg);
  stage_V1(Vbase, rV, sbase, tg);
  stage_K1(Kbase, nK, sbase + 64, tg);
  stage_V1(Vbase, nV, sbase + 64, tg);
  asm volatile("s_waitcnt vmcnt(2)" ::: "memory");
  __builtin_amdgcn_s_barrier();
  __builtin_amdgcn_sched_barrier(0);

  const int NT = LSEQ / 2 / 64;  // 16 tiles per group
  for (int kt = 0; kt < NT; ++kt) {
    if (kt + 2 < NT) {
      stage_K1(Kbase, sK, sbase + (kt + 2) * 64, tg);
      stage_V1(Vbase, sV, sbase + (kt + 2) * 64, tg);
    }
    const unsigned short* lsK = rK;
    const unsigned short* lsV = rV;

    // ---- QK^T (kZero C-in) ----
    bf8_t kf[2][4];
#pragma unroll
    for (int sh = 0; sh < 2; ++sh)
#pragma unroll
      for (int kst = 0; kst < 4; ++kst) {
        const int row = 32 * sh + qn;
        const int ch = (2 * kst + hi) ^ (row & 7);
        kf[sh][kst] = *(const bf8_t*)(&lsK[row * 64 + ch * 8]);
      }
    f16_t sacc[2];
#pragma unroll
    for (int sh = 0; sh < 2; ++sh) {
      sacc[sh] = __builtin_amdgcn_mfma_f32_32x32x16_bf16(kf[sh][0], qf[0], kZero, 0, 0, 0);
#pragma unroll
      for (int kst = 1; kst < 4; ++kst)
        sacc[sh] = __builtin_amdgcn_mfma_f32_32x32x16_bf16(kf[sh][kst], qf[kst], sacc[sh], 0, 0, 0);
    }

    // ---- softmax numerator: P = 2^S2 (fixed max), l per-lane ----
    unsigned int pk[16];
#pragma unroll
    for (int sh = 0; sh < 2; ++sh)
#pragma unroll
      for (int i = 0; i < 8; ++i) {
        const float a = __builtin_amdgcn_exp2f(sacc[sh][2 * i]);
        const float b = __builtin_amdgcn_exp2f(sacc[sh][2 * i + 1]);
        l_lane += a + b;
        pk[sh * 8 + i] = pack2bf(a, b);
      }

    // ---- PV B-frags: zero-shuffle — lane's own pk words ----
    bf8_t pvb[4];
#pragma unroll
    for (int t2 = 0; t2 < 4; ++t2) {
      union { u32x4 u; bf8_t b; } pb;
      pb.u[0] = pk[4 * t2 + 0];
      pb.u[1] = pk[4 * t2 + 1];
      pb.u[2] = pk[4 * t2 + 2];
      pb.u[3] = pk[4 * t2 + 3];
      pvb[t2] = pb.b;
    }

    // ---- PV: V A-frag = ONE b128 (s-permuted storage) ----
#pragma unroll
    for (int eh = 0; eh < 2; ++eh)
#pragma unroll
      for (int t2 = 0; t2 < 4; ++t2) {
        const int row = 32 * eh + qn;
        const int ch = (2 * t2 + hi) ^ (row & 7);
        const bf8_t vf = *(const bf8_t*)(&lsV[row * 64 + ch * 8]);
        oacc[eh] = __builtin_amdgcn_mfma_f32_32x32x16_bf16(vf, pvb[t2], oacc[eh], 0, 0, 0);
      }

    // ---- end-of-iter sync: tile kt+1 resident, my reads of buf kt done ----
    if (kt + 2 < NT) {
      asm volatile("s_waitcnt vmcnt(2) lgkmcnt(0)" ::: "memory");
    } else if (kt + 1 < NT) {
      asm volatile("s_waitcnt vmcnt(0) lgkmcnt(0)" ::: "memory");
    } else {
      asm volatile("s_waitcnt lgkmcnt(0)" ::: "memory");
    }
    __builtin_amdgcn_s_barrier();
    __builtin_amdgcn_sched_barrier(0);

    // rotate buffers
    unsigned short* tK = rK; unsigned short* tV = rV;
    rK = nK; rV = nV;
    nK = sK; nV = sV;
    sK = tK; sV = tV;
  }

  __syncthreads();   // stg reused below

  // ---- combine the two KV halves through LDS (additive: fixed max) ----
  const float l_own = l_lane + __shfl_xor(l_lane, 32);
  float* xO = (float*)&stg[0][0][0][0];        // [256 q][XSTR] floats (69.6 KB)
  float* xL = xO + 256 * XSTR;                 // [256] floats

  if (wg == 1) {
#pragma unroll
    for (int eh = 0; eh < 2; ++eh)
#pragma unroll
      for (int k = 0; k < 4; ++k) {
        float4 v4;
        v4.x = oacc[eh][4 * k + 0]; v4.y = oacc[eh][4 * k + 1];
        v4.z = oacc[eh][4 * k + 2]; v4.w = oacc[eh][4 * k + 3];
        *(float4*)(xO + (wq * 32 + qn) * XSTR + 32 * eh + 8 * k + 4 * hi) = v4;
      }
    if (hi == 0) xL[wq * 32 + qn] = l_own;
  }
  __syncthreads();

  if (wg == 0) {
    const float inv = 1.f / (l_own + xL[wq * 32 + qn]);
    const int b = bh >> 3, h = bh & 7;
#pragma unroll
    for (int eh = 0; eh < 2; ++eh)
#pragma unroll
      for (int k = 0; k < 4; ++k) {
        const float4 v4 = *(const float4*)(xO + (wq * 32 + qn) * XSTR + 32 * eh + 8 * k + 4 * hi);
        ushort4 ov;
        ov.x = f2bf((oacc[eh][4 * k + 0] + v4.x) * inv);
        ov.y = f2bf((oacc[eh][4 * k + 1] + v4.y) * inv);
        ov.z = f2bf((oacc[eh][4 * k + 2] + v4.z) * inv);
        ov.w = f2bf((oacc[eh][4 * k + 3] + v4.w) * inv);
        const int e = 32 * eh + 8 * k + 4 * hi;
        *(ushort4*)(Ao + ((size_t)(b * LSEQ + q0 + qn)) * D_MODEL + h * EDIM + e) = ov;
      }
  }
}

extern "C" void kernel_launch(void* const* d_in, const int* in_sizes, int n_in,
                              void* d_out, int out_size, void* d_ws, size_t ws_size,
                              hipStream_t stream) {
  const float* queries = (const float*)d_in[0];
  const float* keys    = (const float*)d_in[1];
  const float* values  = (const float*)d_in[2];
  const float* Wq = (const float*)d_in[3];
  const float* bq = (const float*)d_in[4];
  const float* Wk = (const float*)d_in[5];
  const float* bk = (const float*)d_in[6];
  const float* Wv = (const float*)d_in[7];
  const float* bv = (const float*)d_in[8];
  const float* Wo = (const float*)d_in[9];
  const float* bo = (const float*)d_in[10];

  char* ws = (char*)d_ws;
  const size_t XSZ = (size_t)MTOT * D_MODEL * 2;  // 8 MB
  unsigned short* Xq  = (unsigned short*)(ws + 0 * XSZ);
  unsigned short* Xk  = (unsigned short*)(ws + 1 * XSZ);
  unsigned short* Xv  = (unsigned short*)(ws + 2 * XSZ);
  unsigned short* Qh  = (unsigned short*)(ws + 3 * XSZ);
  unsigned short* Kh  = (unsigned short*)(ws + 4 * XSZ);
  unsigned short* Vt  = (unsigned short*)(ws + 5 * XSZ);
  unsigned short* Ao  = (unsigned short*)(ws + 6 * XSZ);
  unsigned short* Wqt = (unsigned short*)(ws + 7 * XSZ);
  unsigned short* Wkt = Wqt + 512 * 512;
  unsigned short* Wvt = Wkt + 512 * 512;
  unsigned short* Wot = Wvt + 512 * 512;

  prep_all<<<12544, 256, 0, stream>>>(queries, keys, values, Wq, Wk, Wv, Wo,
                                      Xq, Xk, Xv, Wqt, Wkt, Wvt, Wot);

  qkv_gemm<<<1536, 256, 0, stream>>>(
      Xq, Xk, Xv, Wqt, Wkt, Wvt, bq, bk, bv, Qh, Kh, Vt);

  flash_attn<<<256, 1024, 0, stream>>>(Qh, Kh, Vt, Ao);

  o_gemm<<<512, 256, 0, stream>>>(Ao, Wot, bo, (float*)d_out);
}